// Round 16
// baseline (822.646 us; speedup 1.0000x reference)
//
#include <hip/hip_runtime.h>
#include <hip/hip_bf16.h>
#include <hip/hip_fp16.h>

#define NN 100000
#define EE 1600000
#define GG 512
#define DIN 78
#define DF 32
#define DOUT 128
#define BN_EPS 1e-5f

#define NBLK_NODE 3125      // NN / 32

#define BSH 9               // 512 nodes per bucket
#define NBUCK 196           // ceil(100000 / 512)
#define SCB 256             // scatter blocks
#define EPB (EE / SCB)      // 6250 edges per scatter block

__device__ __forceinline__ unsigned short f2h(float f) {
    return __half_as_ushort(__float2half(f));
}
__device__ __forceinline__ float hlo(unsigned int v) {
    return __half2float(__ushort_as_half((unsigned short)(v & 0xFFFFu)));
}
__device__ __forceinline__ float hhi(unsigned int v) {
    return __half2float(__ushort_as_half((unsigned short)(v >> 16)));
}

// ---------------------------------------------------------------- CSR build (bucketed)
__global__ __launch_bounds__(256) void k_bhist(const int* __restrict__ dst, int* __restrict__ hist_g) {
    __shared__ int hist[NBUCK];
    int tid = threadIdx.x, blk = blockIdx.x;
    if (tid < NBUCK) hist[tid] = 0;
    __syncthreads();
    int start = blk * EPB, end = start + EPB;
    for (int i = start + tid; i < end; i += 256) atomicAdd(&hist[dst[i] >> BSH], 1);
    __syncthreads();
    if (tid < NBUCK) hist_g[tid * SCB + blk] = hist[tid];
}

__global__ __launch_bounds__(256) void k_bscan(int* __restrict__ hist_g, int* __restrict__ bbase) {
    __shared__ int tot[256];
    int t = threadIdx.x;
    int total = 0;
    if (t < NBUCK)
        for (int blk = 0; blk < SCB; ++blk) total += hist_g[t * SCB + blk];
    tot[t] = (t < NBUCK) ? total : 0;
    __syncthreads();
    for (int off = 1; off < 256; off <<= 1) {
        int u = (t >= off) ? tot[t - off] : 0;
        __syncthreads();
        tot[t] += u;
        __syncthreads();
    }
    int excl = tot[t] - total;
    if (t < NBUCK) {
        bbase[t] = excl;
        int run = excl;
        for (int blk = 0; blk < SCB; ++blk) {
            int h = hist_g[t * SCB + blk];
            hist_g[t * SCB + blk] = run;
            run += h;
        }
    }
    if (t == 0) bbase[NBUCK] = EE;
}

__global__ __launch_bounds__(256) void k_bscatter(const int* __restrict__ src, const int* __restrict__ dst,
                                                  const int* __restrict__ hist_g, int* __restrict__ pairs) {
    __shared__ int base_l[NBUCK];
    __shared__ int cnt[NBUCK];
    int tid = threadIdx.x, blk = blockIdx.x;
    if (tid < NBUCK) { base_l[tid] = hist_g[tid * SCB + blk]; cnt[tid] = 0; }
    __syncthreads();
    int start = blk * EPB, end = start + EPB;
    for (int i = start + tid; i < end; i += 256) {
        int d = dst[i], s = src[i];
        int b = d >> BSH;
        int rk = atomicAdd(&cnt[b], 1);
        pairs[base_l[b] + rk] = s | ((d & 511) << 17);
    }
}

// Per bucket: per-(node,quarter) count + scan -> row_ptr + packed quarter counts;
// fill col quarter-ordered within each node's list.
__global__ __launch_bounds__(256) void k_bfill(const int* __restrict__ pairs, const int* __restrict__ bbase,
                                               int* __restrict__ row_ptr, int* __restrict__ qoff,
                                               int* __restrict__ col) {
    __shared__ int c4[2048];      // [node][quarter] counts -> cursors (bucket-local)
    __shared__ int nstart[512];   // bucket-local node start
    __shared__ int ps[256];
    int tid = threadIdx.x, b = blockIdx.x;
    int base = bbase[b];
    int cntb = bbase[b + 1] - base;
    int nbase = b << BSH;
    int nloc = NN - nbase; if (nloc > 512) nloc = 512;
    for (int i = tid; i < 2048; i += 256) c4[i] = 0;
    __syncthreads();
    for (int i = tid; i < cntb; i += 256) {
        int v = pairs[base + i];
        int dloc = (unsigned)v >> 17;
        int q = (v & 0x1FFFF) >> 15;
        atomicAdd(&c4[dloc * 4 + q], 1);
    }
    __syncthreads();
    int n0 = 2 * tid, n1 = 2 * tid + 1;
    int t0 = c4[n0 * 4] + c4[n0 * 4 + 1] + c4[n0 * 4 + 2] + c4[n0 * 4 + 3];
    int t1 = c4[n1 * 4] + c4[n1 * 4 + 1] + c4[n1 * 4 + 2] + c4[n1 * 4 + 3];
    ps[tid] = t0 + t1;
    __syncthreads();
    for (int off = 1; off < 256; off <<= 1) {
        int u = (tid >= off) ? ps[tid - off] : 0;
        __syncthreads();
        ps[tid] += u;
        __syncthreads();
    }
    int pexcl = ps[tid] - (t0 + t1);
    nstart[n0] = pexcl;
    nstart[n1] = pexcl + t0;
    // counts -> cursors for this thread's two nodes (exclusive ownership)
    #pragma unroll
    for (int kk = 0; kk < 2; ++kk) {
        int n = (kk == 0) ? n0 : n1;
        if (n < nloc) {
            int s = nstart[n];
            int c0 = c4[n * 4], c1 = c4[n * 4 + 1], c2 = c4[n * 4 + 2];
            c4[n * 4]     = s;
            c4[n * 4 + 1] = s + c0;
            c4[n * 4 + 2] = s + c0 + c1;
            c4[n * 4 + 3] = s + c0 + c1 + c2;
            row_ptr[nbase + n] = base + s;
            qoff[nbase + n] = c0 | (c1 << 8) | (c2 << 16);
        }
    }
    if (b == 0 && tid == 0) row_ptr[NN] = EE;
    __syncthreads();
    for (int i = tid; i < cntb; i += 256) {
        int v = pairs[base + i];
        int dloc = (unsigned)v >> 17;
        int s = v & 0x1FFFF;
        int q = s >> 15;
        int lp = atomicAdd(&c4[dloc * 4 + q], 1);
        col[base + lp] = s;
    }
}

// ---------------------------------------------------------------- layer kernels
// p = x @ w1  (layer 1).  Writes f32 p and fp16 pb.
__global__ __launch_bounds__(256) void k_proj_first(const float* __restrict__ x,
                                                    const float* __restrict__ w1,
                                                    float* __restrict__ p,
                                                    unsigned short* __restrict__ pb) {
    __shared__ float w[DIN][DF];
    __shared__ float hx[32][DIN];
    int tid = threadIdx.x;
    for (int i = tid; i < DIN * DF; i += 256) w[i >> 5][i & 31] = w1[i];
    int base = blockIdx.x * 32;
    for (int i = tid; i < 32 * DIN; i += 256) hx[i / DIN][i % DIN] = x[base * DIN + i];
    __syncthreads();
    int j = tid & 31;
    #pragma unroll
    for (int it = 0; it < 4; ++it) {
        int rown = (tid >> 5) + 8 * it;
        float acc = 0.f;
        #pragma unroll
        for (int k = 0; k < DIN; ++k) acc += hx[rown][k] * w[k][j];
        p[(base + rown) * DF + j] = acc;
        pb[(base + rown) * DF + j] = f2h(acc);
    }
}

// p = BN(r) @ w1  (hidden layers).  Writes f32 p and fp16 pb.
__global__ __launch_bounds__(256) void k_proj_hidden(const float* __restrict__ r,
                                                     const float* __restrict__ w1_,
                                                     const float* __restrict__ statsL,
                                                     const float* __restrict__ gamma,
                                                     const float* __restrict__ beta,
                                                     float* __restrict__ p,
                                                     unsigned short* __restrict__ pb) {
    __shared__ float w[DF][DF];
    __shared__ float h[32][DF + 1];
    int tid = threadIdx.x;
    for (int i = tid; i < DF * DF; i += 256) w[i >> 5][i & 31] = w1_[i];
    int grp = tid >> 3, c = tid & 7;
    int node = blockIdx.x * 32 + grp;
    const float invN = 1.0f / (float)NN;
    float4 s1v = ((const float4*)statsL)[c];
    float4 s2v = ((const float4*)(statsL + DF))[c];
    float4 gv  = ((const float4*)gamma)[c];
    float4 bv  = ((const float4*)beta)[c];
    float4 rv  = ((const float4*)r)[node * 8 + c];
    float mux = s1v.x * invN, muy = s1v.y * invN, muz = s1v.z * invN, muw = s1v.w * invN;
    float ivx = rsqrtf(s2v.x * invN - mux * mux + BN_EPS);
    float ivy = rsqrtf(s2v.y * invN - muy * muy + BN_EPS);
    float ivz = rsqrtf(s2v.z * invN - muz * muz + BN_EPS);
    float ivw = rsqrtf(s2v.w * invN - muw * muw + BN_EPS);
    h[grp][4 * c + 0] = gv.x * (rv.x - mux) * ivx + bv.x;
    h[grp][4 * c + 1] = gv.y * (rv.y - muy) * ivy + bv.y;
    h[grp][4 * c + 2] = gv.z * (rv.z - muz) * ivz + bv.z;
    h[grp][4 * c + 3] = gv.w * (rv.w - muw) * ivw + bv.w;
    __syncthreads();
    int j = tid & 31;
    #pragma unroll
    for (int it = 0; it < 4; ++it) {
        int rown = (tid >> 5) + 8 * it;
        float acc = 0.f;
        #pragma unroll
        for (int k = 0; k < DF; ++k) acc += h[rown][k] * w[k][j];
        p[(blockIdx.x * 32 + rown) * DF + j] = acc;
        pb[(blockIdx.x * 32 + rown) * DF + j] = f2h(acc);
    }
}

// agg: 32 nodes/block, 8-lane group per node, register accumulate, 4-way ILP,
// fp16 gathers, and QUARTER-PHASED walk (src>>15) with block-level barriers so
// concurrent blocks gather from the same ~2MB window (L2-resident).
__global__ __launch_bounds__(256) void k_agg(const float* __restrict__ p,
                                             const unsigned short* __restrict__ pb,
                                             const int* __restrict__ row_ptr,
                                             const int* __restrict__ qoff,
                                             const int* __restrict__ col,
                                             const float* __restrict__ b1,
                                             const float* __restrict__ w2_,
                                             const float* __restrict__ b2,
                                             float* __restrict__ r,
                                             float* __restrict__ statsL) {
    __shared__ float w[DF][DF];
    __shared__ float a[32][DF + 1];
    __shared__ float red[4][2][DF];
    int tid = threadIdx.x;
    for (int i = tid; i < DF * DF; i += 256) w[i >> 5][i & 31] = w2_[i];
    int grp = tid >> 3, c = tid & 7;
    int base = blockIdx.x * 32;
    int node = base + grp;
    const float4* p4 = (const float4*)p;
    const uint2* pb2 = (const uint2*)pb;   // 8 uint2 per node (64 B)
    float4 b1v = ((const float4*)b1)[c];
    float4 self = p4[node * 8 + c];
    float4 acc0, acc1, acc2, acc3;
    acc0.x = self.x + b1v.x; acc0.y = self.y + b1v.y;
    acc0.z = self.z + b1v.z; acc0.w = self.w + b1v.w;
    acc1.x = acc1.y = acc1.z = acc1.w = 0.f;
    acc2.x = acc2.y = acc2.z = acc2.w = 0.f;
    acc3.x = acc3.y = acc3.z = acc3.w = 0.f;
    int e0 = row_ptr[node], e1 = row_ptr[node + 1];
    int qc = qoff[node];
    int q1 = e0 + (qc & 255);
    int q2 = q1 + ((qc >> 8) & 255);
    int q3 = q2 + ((qc >> 16) & 255);

    auto walk = [&](int s, int t) {
        int e = s;
        for (; e + 4 <= t; e += 4) {
            int s0 = col[e], s1 = col[e + 1], s2 = col[e + 2], s3 = col[e + 3];
            uint2 v0 = pb2[s0 * 8 + c];
            uint2 v1 = pb2[s1 * 8 + c];
            uint2 v2 = pb2[s2 * 8 + c];
            uint2 v3 = pb2[s3 * 8 + c];
            acc0.x += hlo(v0.x); acc0.y += hhi(v0.x); acc0.z += hlo(v0.y); acc0.w += hhi(v0.y);
            acc1.x += hlo(v1.x); acc1.y += hhi(v1.x); acc1.z += hlo(v1.y); acc1.w += hhi(v1.y);
            acc2.x += hlo(v2.x); acc2.y += hhi(v2.x); acc2.z += hlo(v2.y); acc2.w += hhi(v2.y);
            acc3.x += hlo(v3.x); acc3.y += hhi(v3.x); acc3.z += hlo(v3.y); acc3.w += hhi(v3.y);
        }
        for (; e < t; ++e) {
            uint2 v = pb2[col[e] * 8 + c];
            acc0.x += hlo(v.x); acc0.y += hhi(v.x); acc0.z += hlo(v.y); acc0.w += hhi(v.y);
        }
    };
    walk(e0, q1);
    __syncthreads();
    walk(q1, q2);
    __syncthreads();
    walk(q2, q3);
    __syncthreads();
    walk(q3, e1);

    acc0.x += acc1.x + acc2.x + acc3.x;
    acc0.y += acc1.y + acc2.y + acc3.y;
    acc0.z += acc1.z + acc2.z + acc3.z;
    acc0.w += acc1.w + acc2.w + acc3.w;
    a[grp][4 * c + 0] = fmaxf(acc0.x, 0.f);
    a[grp][4 * c + 1] = fmaxf(acc0.y, 0.f);
    a[grp][4 * c + 2] = fmaxf(acc0.z, 0.f);
    a[grp][4 * c + 3] = fmaxf(acc0.w, 0.f);
    __syncthreads();
    int j = tid & 31;
    float b2j = b2[j];
    float s1 = 0.f, s2 = 0.f;
    #pragma unroll
    for (int it = 0; it < 4; ++it) {
        int rown = (tid >> 5) + 8 * it;
        float accm = b2j;
        #pragma unroll
        for (int k = 0; k < DF; ++k) accm += a[rown][k] * w[k][j];
        float rv = fmaxf(accm, 0.f);
        r[(base + rown) * DF + j] = rv;
        s1 += rv;
        s2 += rv * rv;
    }
    s1 += __shfl_down(s1, 32);
    s2 += __shfl_down(s2, 32);
    int wave = tid >> 6, lane = tid & 63;
    if (lane < 32) { red[wave][0][j] = s1; red[wave][1][j] = s2; }
    __syncthreads();
    if (tid < 32) {
        float t1 = red[0][0][j] + red[1][0][j] + red[2][0][j] + red[3][0][j];
        float t2 = red[0][1][j] + red[1][1][j] + red[2][1][j] + red[3][1][j];
        atomicAdd(&statsL[j], t1);
        atomicAdd(&statsL[DF + j], t2);
    }
}

// BN-apply (layer-5 sums) + global_add_pool; run-length accumulate.
__global__ __launch_bounds__(256) void k_pool(const float* __restrict__ r,
                                              const float* __restrict__ statsL,
                                              const float* __restrict__ gamma,
                                              const float* __restrict__ beta,
                                              const int* __restrict__ batch,
                                              float* __restrict__ pooled) {
    int t = blockIdx.x * 256 + threadIdx.x;
    int nodeBase = (t >> 5) * 8;
    if (nodeBase >= NN) return;
    int j = t & 31;
    const float invN = 1.0f / (float)NN;
    float mu = statsL[j] * invN;
    float inv = rsqrtf(statsL[DF + j] * invN - mu * mu + BN_EPS);
    float gj = gamma[j], bj = beta[j];
    float accp = 0.f;
    int curg = batch[nodeBase];
    #pragma unroll
    for (int k = 0; k < 8; ++k) {
        int n = nodeBase + k;
        int g = batch[n];
        float val = gj * (r[n * DF + j] - mu) * inv + bj;
        if (g != curg) { atomicAdd(&pooled[curg * DF + j], accp); accp = 0.f; curg = g; }
        accp += val;
    }
    atomicAdd(&pooled[curg * DF + j], accp);
}

__global__ __launch_bounds__(128) void k_fc(const float* __restrict__ pooled,
                                            const float* __restrict__ fc_w,
                                            const float* __restrict__ fc_b,
                                            float* __restrict__ out) {
    __shared__ float pl[DF];
    int g = blockIdx.x, j = threadIdx.x;
    if (j < DF) pl[j] = pooled[g * DF + j];
    __syncthreads();
    float acc = fc_b[j];
    #pragma unroll
    for (int k = 0; k < DF; ++k) acc += pl[k] * fc_w[k * DOUT + j];
    out[g * DOUT + j] = fmaxf(acc, 0.f);
}

// ---------------------------------------------------------------- host
extern "C" void kernel_launch(void* const* d_in, const int* in_sizes, int n_in,
                              void* d_out, int out_size, void* d_ws, size_t ws_size,
                              hipStream_t stream) {
    const float* x      = (const float*)d_in[0];
    const int*   eidx   = (const int*)d_in[1];
    const int*   batch  = (const int*)d_in[2];
    const float* w1_in  = (const float*)d_in[3];
    const float* b1_in  = (const float*)d_in[4];
    const float* w1_out = (const float*)d_in[5];
    const float* b1_out = (const float*)d_in[6];
    const float* wa     = (const float*)d_in[7];
    const float* ba     = (const float*)d_in[8];
    const float* wb     = (const float*)d_in[9];
    const float* bb     = (const float*)d_in[10];
    const float* gamma  = (const float*)d_in[11];
    const float* beta   = (const float*)d_in[12];
    const float* fc_w   = (const float*)d_in[13];
    const float* fc_b   = (const float*)d_in[14];
    float* out = (float*)d_out;

    const int* esrc = eidx;
    const int* edst = eidx + EE;

    // workspace carve-up
    float* W = (float*)d_ws;
    float* p       = W;                         // NN*DF floats (pairs overlay during CSR build)
    float* r       = p + (size_t)NN * DF;       // NN*DF
    float* pooled  = r + (size_t)NN * DF;       // GG*DF
    float* stats   = pooled + (size_t)GG * DF;  // 5*64 (s1|s2 per layer)
    int* row_ptr = (int*)(stats + 5 * 64);      // NN+1
    int* col     = row_ptr + (NN + 1);          // EE
    int* hist_g  = col + EE;                    // NBUCK*SCB
    int* bbase   = hist_g + NBUCK * SCB;        // NBUCK+1
    unsigned short* pb = (unsigned short*)(bbase + NBUCK + 1);  // NN*DF fp16 (6.4 MB)
    int* qoff    = (int*)(pb + (size_t)NN * DF);                // NN packed quarter counts
    int* pairs   = (int*)p;                     // EE ints == 6.4 MB, overlays p

    // ---- CSR build (bucketed, quarter-ordered; same work every call) ----
    k_bhist<<<SCB, 256, 0, stream>>>(edst, hist_g);
    k_bscan<<<1, 256, 0, stream>>>(hist_g, bbase);
    k_bscatter<<<SCB, 256, 0, stream>>>(esrc, edst, hist_g, pairs);
    k_bfill<<<NBUCK, 256, 0, stream>>>(pairs, bbase, row_ptr, qoff, col);

    hipMemsetAsync(stats, 0, sizeof(float) * 5 * 64, stream);

    // ---- layer 1 ----
    k_proj_first<<<NBLK_NODE, 256, 0, stream>>>(x, w1_in, p, pb);
    k_agg<<<NBLK_NODE, 256, 0, stream>>>(p, pb, row_ptr, qoff, col, b1_in, w1_out, b1_out, r, stats);

    // ---- layers 2..5 ----
    for (int i = 1; i < 5; ++i) {
        const float* w1_ = wa + (size_t)(i - 1) * DF * DF;
        const float* b1_ = ba + (size_t)(i - 1) * DF;
        const float* w2_ = wb + (size_t)(i - 1) * DF * DF;
        const float* b2_ = bb + (size_t)(i - 1) * DF;
        const float* g_  = gamma + (size_t)(i - 1) * DF;
        const float* be_ = beta + (size_t)(i - 1) * DF;
        k_proj_hidden<<<NBLK_NODE, 256, 0, stream>>>(r, w1_, stats + (i - 1) * 64, g_, be_, p, pb);
        k_agg<<<NBLK_NODE, 256, 0, stream>>>(p, pb, row_ptr, qoff, col, b1_, w2_, b2_, r, stats + i * 64);
    }

    // ---- pool (+ BN of layer 5) and FC ----
    hipMemsetAsync(pooled, 0, sizeof(float) * GG * DF, stream);
    k_pool<<<((NN / 8) * 32 + 255) / 256, 256, 0, stream>>>(r, stats + 4 * 64, gamma + 4 * DF,
                                                            beta + 4 * DF, batch, pooled);
    k_fc<<<GG, 128, 0, stream>>>(pooled, fc_w, fc_b, out);
}

// Round 18
// 773.527 us; speedup vs baseline: 1.0635x; 1.0635x over previous
//
#include <hip/hip_runtime.h>
#include <hip/hip_bf16.h>
#include <hip/hip_fp16.h>

#define NN 100000
#define EE 1600000
#define GG 512
#define DIN 78
#define DF 32
#define DOUT 128
#define BN_EPS 1e-5f

#define NBLK_NODE 3125      // NN / 32
#define HALF_N 50000        // src-window split for 2-phase agg

#define BSH 9               // 512 nodes per bucket
#define NBUCK 196           // ceil(100000 / 512)
#define SCB 256             // scatter blocks
#define EPB (EE / SCB)      // 6250 edges per scatter block

__device__ __forceinline__ unsigned short f2h(float f) {
    return __half_as_ushort(__float2half(f));
}
__device__ __forceinline__ float hlo(unsigned int v) {
    return __half2float(__ushort_as_half((unsigned short)(v & 0xFFFFu)));
}
__device__ __forceinline__ float hhi(unsigned int v) {
    return __half2float(__ushort_as_half((unsigned short)(v >> 16)));
}

// ---------------------------------------------------------------- CSR build (bucketed)
__global__ __launch_bounds__(256) void k_bhist(const int* __restrict__ dst, int* __restrict__ hist_g) {
    __shared__ int hist[NBUCK];
    int tid = threadIdx.x, blk = blockIdx.x;
    if (tid < NBUCK) hist[tid] = 0;
    __syncthreads();
    int start = blk * EPB, end = start + EPB;
    for (int i = start + tid; i < end; i += 256) atomicAdd(&hist[dst[i] >> BSH], 1);
    __syncthreads();
    if (tid < NBUCK) hist_g[tid * SCB + blk] = hist[tid];
}

// Parallel two-level scan of hist_g rows: A) per-bucket row scan, B) bucket bases.
__global__ __launch_bounds__(256) void k_bscanA(int* __restrict__ hist_g, int* __restrict__ bbase) {
    __shared__ int s[256];
    int t = threadIdx.x, b = blockIdx.x;
    int v = hist_g[b * SCB + t];
    s[t] = v;
    __syncthreads();
    for (int off = 1; off < 256; off <<= 1) {
        int u = (t >= off) ? s[t - off] : 0;
        __syncthreads();
        s[t] += u;
        __syncthreads();
    }
    hist_g[b * SCB + t] = s[t] - v;     // exclusive prefix within bucket
    if (t == 255) bbase[b] = s[t];      // bucket total
}

__global__ __launch_bounds__(256) void k_bscanB(int* __restrict__ bbase) {
    __shared__ int s[256];
    int t = threadIdx.x;
    int v = (t < NBUCK) ? bbase[t] : 0;
    s[t] = v;
    __syncthreads();
    for (int off = 1; off < 256; off <<= 1) {
        int u = (t >= off) ? s[t - off] : 0;
        __syncthreads();
        s[t] += u;
        __syncthreads();
    }
    if (t < NBUCK) bbase[t] = s[t] - v;  // exclusive bases
    if (t == 0) bbase[NBUCK] = EE;
}

__global__ __launch_bounds__(256) void k_bscatter(const int* __restrict__ src, const int* __restrict__ dst,
                                                  const int* __restrict__ hist_g, const int* __restrict__ bbase,
                                                  int* __restrict__ pairs) {
    __shared__ int base_l[NBUCK];
    __shared__ int cnt[NBUCK];
    int tid = threadIdx.x, blk = blockIdx.x;
    if (tid < NBUCK) { base_l[tid] = bbase[tid] + hist_g[tid * SCB + blk]; cnt[tid] = 0; }
    __syncthreads();
    int start = blk * EPB, end = start + EPB;
    for (int i = start + tid; i < end; i += 256) {
        int d = dst[i], s = src[i];
        int b = d >> BSH;
        int rk = atomicAdd(&cnt[b], 1);
        pairs[base_l[b] + rk] = s | ((d & 511) << 17);
    }
}

// Per bucket: per-(node,half) count + scan -> row_ptr + first-half count; fill col
// half-ordered within each node's list.
__global__ __launch_bounds__(256) void k_bfill(const int* __restrict__ pairs, const int* __restrict__ bbase,
                                               int* __restrict__ row_ptr, int* __restrict__ qoff,
                                               int* __restrict__ col) {
    __shared__ int c2[1024];      // [node][half] counts -> cursors (bucket-local)
    __shared__ int nstart[512];
    __shared__ int ps[256];
    int tid = threadIdx.x, b = blockIdx.x;
    int base = bbase[b];
    int cntb = bbase[b + 1] - base;
    int nbase = b << BSH;
    int nloc = NN - nbase; if (nloc > 512) nloc = 512;
    for (int i = tid; i < 1024; i += 256) c2[i] = 0;
    __syncthreads();
    for (int i = tid; i < cntb; i += 256) {
        int v = pairs[base + i];
        int dloc = (unsigned)v >> 17;
        int q = ((v & 0x1FFFF) >= HALF_N) ? 1 : 0;
        atomicAdd(&c2[dloc * 2 + q], 1);
    }
    __syncthreads();
    int n0 = 2 * tid, n1 = 2 * tid + 1;
    int t0 = c2[n0 * 2] + c2[n0 * 2 + 1];
    int t1 = c2[n1 * 2] + c2[n1 * 2 + 1];
    ps[tid] = t0 + t1;
    __syncthreads();
    for (int off = 1; off < 256; off <<= 1) {
        int u = (tid >= off) ? ps[tid - off] : 0;
        __syncthreads();
        ps[tid] += u;
        __syncthreads();
    }
    int pexcl = ps[tid] - (t0 + t1);
    nstart[n0] = pexcl;
    nstart[n1] = pexcl + t0;
    #pragma unroll
    for (int kk = 0; kk < 2; ++kk) {
        int n = (kk == 0) ? n0 : n1;
        if (n < nloc) {
            int s = nstart[n];
            int c0 = c2[n * 2];
            c2[n * 2]     = s;
            c2[n * 2 + 1] = s + c0;
            row_ptr[nbase + n] = base + s;
            qoff[nbase + n] = c0;
        }
    }
    if (b == 0 && tid == 0) row_ptr[NN] = EE;
    __syncthreads();
    for (int i = tid; i < cntb; i += 256) {
        int v = pairs[base + i];
        int dloc = (unsigned)v >> 17;
        int s = v & 0x1FFFF;
        int q = (s >= HALF_N) ? 1 : 0;
        int lp = atomicAdd(&c2[dloc * 2 + q], 1);
        col[base + lp] = s;
    }
}

// ---------------------------------------------------------------- layer kernels
// p = x @ w1  (layer 1).  Writes f32 p and fp16 pb.
__global__ __launch_bounds__(256) void k_proj_first(const float* __restrict__ x,
                                                    const float* __restrict__ w1,
                                                    float* __restrict__ p,
                                                    unsigned short* __restrict__ pb) {
    __shared__ float w[DIN][DF];
    __shared__ float hx[32][DIN];
    int tid = threadIdx.x;
    for (int i = tid; i < DIN * DF; i += 256) w[i >> 5][i & 31] = w1[i];
    int base = blockIdx.x * 32;
    for (int i = tid; i < 32 * DIN; i += 256) hx[i / DIN][i % DIN] = x[base * DIN + i];
    __syncthreads();
    int j = tid & 31;
    #pragma unroll
    for (int it = 0; it < 4; ++it) {
        int rown = (tid >> 5) + 8 * it;
        float acc = 0.f;
        #pragma unroll
        for (int k = 0; k < DIN; ++k) acc += hx[rown][k] * w[k][j];
        p[(base + rown) * DF + j] = acc;
        pb[(base + rown) * DF + j] = f2h(acc);
    }
}

// p = BN(r) @ w1  (hidden layers).  Writes f32 p and fp16 pb.
__global__ __launch_bounds__(256) void k_proj_hidden(const float* __restrict__ r,
                                                     const float* __restrict__ w1_,
                                                     const float* __restrict__ statsL,
                                                     const float* __restrict__ gamma,
                                                     const float* __restrict__ beta,
                                                     float* __restrict__ p,
                                                     unsigned short* __restrict__ pb) {
    __shared__ float w[DF][DF];
    __shared__ float h[32][DF + 1];
    int tid = threadIdx.x;
    for (int i = tid; i < DF * DF; i += 256) w[i >> 5][i & 31] = w1_[i];
    int grp = tid >> 3, c = tid & 7;
    int node = blockIdx.x * 32 + grp;
    const float invN = 1.0f / (float)NN;
    float4 s1v = ((const float4*)statsL)[c];
    float4 s2v = ((const float4*)(statsL + DF))[c];
    float4 gv  = ((const float4*)gamma)[c];
    float4 bv  = ((const float4*)beta)[c];
    float4 rv  = ((const float4*)r)[node * 8 + c];
    float mux = s1v.x * invN, muy = s1v.y * invN, muz = s1v.z * invN, muw = s1v.w * invN;
    float ivx = rsqrtf(s2v.x * invN - mux * mux + BN_EPS);
    float ivy = rsqrtf(s2v.y * invN - muy * muy + BN_EPS);
    float ivz = rsqrtf(s2v.z * invN - muz * muz + BN_EPS);
    float ivw = rsqrtf(s2v.w * invN - muw * muw + BN_EPS);
    h[grp][4 * c + 0] = gv.x * (rv.x - mux) * ivx + bv.x;
    h[grp][4 * c + 1] = gv.y * (rv.y - muy) * ivy + bv.y;
    h[grp][4 * c + 2] = gv.z * (rv.z - muz) * ivz + bv.z;
    h[grp][4 * c + 3] = gv.w * (rv.w - muw) * ivw + bv.w;
    __syncthreads();
    int j = tid & 31;
    #pragma unroll
    for (int it = 0; it < 4; ++it) {
        int rown = (tid >> 5) + 8 * it;
        float acc = 0.f;
        #pragma unroll
        for (int k = 0; k < DF; ++k) acc += h[rown][k] * w[k][j];
        p[(blockIdx.x * 32 + rown) * DF + j] = acc;
        pb[(blockIdx.x * 32 + rown) * DF + j] = f2h(acc);
    }
}

// agg: 32 nodes/block, 8-lane group per node, register accumulate, 4-way ILP,
// fp16 gathers, 2-PHASE walk (src window 3.2 MB < 4 MiB per-XCD L2), 1 barrier.
__global__ __launch_bounds__(256) void k_agg(const float* __restrict__ p,
                                             const unsigned short* __restrict__ pb,
                                             const int* __restrict__ row_ptr,
                                             const int* __restrict__ qoff,
                                             const int* __restrict__ col,
                                             const float* __restrict__ b1,
                                             const float* __restrict__ w2_,
                                             const float* __restrict__ b2,
                                             float* __restrict__ r,
                                             float* __restrict__ statsL) {
    __shared__ float w[DF][DF];
    __shared__ float a[32][DF + 1];
    __shared__ float red[4][2][DF];
    int tid = threadIdx.x;
    for (int i = tid; i < DF * DF; i += 256) w[i >> 5][i & 31] = w2_[i];
    int grp = tid >> 3, c = tid & 7;
    int base = blockIdx.x * 32;
    int node = base + grp;
    const float4* p4 = (const float4*)p;
    const uint2* pb2 = (const uint2*)pb;   // 8 uint2 per node (64 B)
    float4 b1v = ((const float4*)b1)[c];
    float4 self = p4[node * 8 + c];
    float4 acc0, acc1, acc2, acc3;
    acc0.x = self.x + b1v.x; acc0.y = self.y + b1v.y;
    acc0.z = self.z + b1v.z; acc0.w = self.w + b1v.w;
    acc1.x = acc1.y = acc1.z = acc1.w = 0.f;
    acc2.x = acc2.y = acc2.z = acc2.w = 0.f;
    acc3.x = acc3.y = acc3.z = acc3.w = 0.f;
    int e0 = row_ptr[node], e1 = row_ptr[node + 1];
    int q1 = e0 + qoff[node];

    auto walk = [&](int s, int t) {
        int e = s;
        for (; e + 4 <= t; e += 4) {
            int s0 = col[e], s1 = col[e + 1], s2 = col[e + 2], s3 = col[e + 3];
            uint2 v0 = pb2[s0 * 8 + c];
            uint2 v1 = pb2[s1 * 8 + c];
            uint2 v2 = pb2[s2 * 8 + c];
            uint2 v3 = pb2[s3 * 8 + c];
            acc0.x += hlo(v0.x); acc0.y += hhi(v0.x); acc0.z += hlo(v0.y); acc0.w += hhi(v0.y);
            acc1.x += hlo(v1.x); acc1.y += hhi(v1.x); acc1.z += hlo(v1.y); acc1.w += hhi(v1.y);
            acc2.x += hlo(v2.x); acc2.y += hhi(v2.x); acc2.z += hlo(v2.y); acc2.w += hhi(v2.y);
            acc3.x += hlo(v3.x); acc3.y += hhi(v3.x); acc3.z += hlo(v3.y); acc3.w += hhi(v3.y);
        }
        for (; e < t; ++e) {
            uint2 v = pb2[col[e] * 8 + c];
            acc0.x += hlo(v.x); acc0.y += hhi(v.x); acc0.z += hlo(v.y); acc0.w += hhi(v.y);
        }
    };
    walk(e0, q1);
    __syncthreads();
    walk(q1, e1);

    acc0.x += acc1.x + acc2.x + acc3.x;
    acc0.y += acc1.y + acc2.y + acc3.y;
    acc0.z += acc1.z + acc2.z + acc3.z;
    acc0.w += acc1.w + acc2.w + acc3.w;
    a[grp][4 * c + 0] = fmaxf(acc0.x, 0.f);
    a[grp][4 * c + 1] = fmaxf(acc0.y, 0.f);
    a[grp][4 * c + 2] = fmaxf(acc0.z, 0.f);
    a[grp][4 * c + 3] = fmaxf(acc0.w, 0.f);
    __syncthreads();
    int j = tid & 31;
    float b2j = b2[j];
    float s1 = 0.f, s2 = 0.f;
    #pragma unroll
    for (int it = 0; it < 4; ++it) {
        int rown = (tid >> 5) + 8 * it;
        float accm = b2j;
        #pragma unroll
        for (int k = 0; k < DF; ++k) accm += a[rown][k] * w[k][j];
        float rv = fmaxf(accm, 0.f);
        r[(base + rown) * DF + j] = rv;
        s1 += rv;
        s2 += rv * rv;
    }
    s1 += __shfl_down(s1, 32);
    s2 += __shfl_down(s2, 32);
    int wave = tid >> 6, lane = tid & 63;
    if (lane < 32) { red[wave][0][j] = s1; red[wave][1][j] = s2; }
    __syncthreads();
    if (tid < 32) {
        float t1 = red[0][0][j] + red[1][0][j] + red[2][0][j] + red[3][0][j];
        float t2 = red[0][1][j] + red[1][1][j] + red[2][1][j] + red[3][1][j];
        atomicAdd(&statsL[j], t1);
        atomicAdd(&statsL[DF + j], t2);
    }
}

// BN-apply (layer-5 sums) + global_add_pool; run-length accumulate.
__global__ __launch_bounds__(256) void k_pool(const float* __restrict__ r,
                                              const float* __restrict__ statsL,
                                              const float* __restrict__ gamma,
                                              const float* __restrict__ beta,
                                              const int* __restrict__ batch,
                                              float* __restrict__ pooled) {
    int t = blockIdx.x * 256 + threadIdx.x;
    int nodeBase = (t >> 5) * 8;
    if (nodeBase >= NN) return;
    int j = t & 31;
    const float invN = 1.0f / (float)NN;
    float mu = statsL[j] * invN;
    float inv = rsqrtf(statsL[DF + j] * invN - mu * mu + BN_EPS);
    float gj = gamma[j], bj = beta[j];
    float accp = 0.f;
    int curg = batch[nodeBase];
    #pragma unroll
    for (int k = 0; k < 8; ++k) {
        int n = nodeBase + k;
        int g = batch[n];
        float val = gj * (r[n * DF + j] - mu) * inv + bj;
        if (g != curg) { atomicAdd(&pooled[curg * DF + j], accp); accp = 0.f; curg = g; }
        accp += val;
    }
    atomicAdd(&pooled[curg * DF + j], accp);
}

__global__ __launch_bounds__(128) void k_fc(const float* __restrict__ pooled,
                                            const float* __restrict__ fc_w,
                                            const float* __restrict__ fc_b,
                                            float* __restrict__ out) {
    __shared__ float pl[DF];
    int g = blockIdx.x, j = threadIdx.x;
    if (j < DF) pl[j] = pooled[g * DF + j];
    __syncthreads();
    float acc = fc_b[j];
    #pragma unroll
    for (int k = 0; k < DF; ++k) acc += pl[k] * fc_w[k * DOUT + j];
    out[g * DOUT + j] = fmaxf(acc, 0.f);
}

// ---------------------------------------------------------------- host
extern "C" void kernel_launch(void* const* d_in, const int* in_sizes, int n_in,
                              void* d_out, int out_size, void* d_ws, size_t ws_size,
                              hipStream_t stream) {
    const float* x      = (const float*)d_in[0];
    const int*   eidx   = (const int*)d_in[1];
    const int*   batch  = (const int*)d_in[2];
    const float* w1_in  = (const float*)d_in[3];
    const float* b1_in  = (const float*)d_in[4];
    const float* w1_out = (const float*)d_in[5];
    const float* b1_out = (const float*)d_in[6];
    const float* wa     = (const float*)d_in[7];
    const float* ba     = (const float*)d_in[8];
    const float* wb     = (const float*)d_in[9];
    const float* bb     = (const float*)d_in[10];
    const float* gamma  = (const float*)d_in[11];
    const float* beta   = (const float*)d_in[12];
    const float* fc_w   = (const float*)d_in[13];
    const float* fc_b   = (const float*)d_in[14];
    float* out = (float*)d_out;

    const int* esrc = eidx;
    const int* edst = eidx + EE;

    // workspace carve-up
    float* W = (float*)d_ws;
    float* p       = W;                         // NN*DF floats (pairs overlay during CSR build)
    float* r       = p + (size_t)NN * DF;       // NN*DF
    float* pooled  = r + (size_t)NN * DF;       // GG*DF
    float* stats   = pooled + (size_t)GG * DF;  // 5*64 (s1|s2 per layer)
    int* row_ptr = (int*)(stats + 5 * 64);      // NN+1
    int* col     = row_ptr + (NN + 1);          // EE
    int* hist_g  = col + EE;                    // NBUCK*SCB
    int* bbase   = hist_g + NBUCK * SCB;        // NBUCK+1
    unsigned short* pb = (unsigned short*)(bbase + NBUCK + 1);  // NN*DF fp16 (6.4 MB)
    int* qoff    = (int*)(pb + (size_t)NN * DF);                // NN first-half counts
    int* pairs   = (int*)p;                     // EE ints == 6.4 MB, overlays p

    // ---- CSR build (bucketed, half-ordered; same work every call) ----
    k_bhist<<<SCB, 256, 0, stream>>>(edst, hist_g);
    k_bscanA<<<NBUCK, 256, 0, stream>>>(hist_g, bbase);
    k_bscanB<<<1, 256, 0, stream>>>(bbase);
    k_bscatter<<<SCB, 256, 0, stream>>>(esrc, edst, hist_g, bbase, pairs);
    k_bfill<<<NBUCK, 256, 0, stream>>>(pairs, bbase, row_ptr, qoff, col);

    hipMemsetAsync(stats, 0, sizeof(float) * 5 * 64, stream);

    // ---- layer 1 ----
    k_proj_first<<<NBLK_NODE, 256, 0, stream>>>(x, w1_in, p, pb);
    k_agg<<<NBLK_NODE, 256, 0, stream>>>(p, pb, row_ptr, qoff, col, b1_in, w1_out, b1_out, r, stats);

    // ---- layers 2..5 ----
    for (int i = 1; i < 5; ++i) {
        const float* w1_ = wa + (size_t)(i - 1) * DF * DF;
        const float* b1_ = ba + (size_t)(i - 1) * DF;
        const float* w2_ = wb + (size_t)(i - 1) * DF * DF;
        const float* b2_ = bb + (size_t)(i - 1) * DF;
        const float* g_  = gamma + (size_t)(i - 1) * DF;
        const float* be_ = beta + (size_t)(i - 1) * DF;
        k_proj_hidden<<<NBLK_NODE, 256, 0, stream>>>(r, w1_, stats + (i - 1) * 64, g_, be_, p, pb);
        k_agg<<<NBLK_NODE, 256, 0, stream>>>(p, pb, row_ptr, qoff, col, b1_, w2_, b2_, r, stats + i * 64);
    }

    // ---- pool (+ BN of layer 5) and FC ----
    hipMemsetAsync(pooled, 0, sizeof(float) * GG * DF, stream);
    k_pool<<<((NN / 8) * 32 + 255) / 256, 256, 0, stream>>>(r, stats + 4 * 64, gamma + 4 * DF,
                                                            beta + 4 * DF, batch, pooled);
    k_fc<<<GG, 128, 0, stream>>>(pooled, fc_w, fc_b, out);
}